// Round 21
// baseline (19.882 us; speedup 1.0000x reference)
//
#include <hip/hip_runtime.h>

#define JITTER 1e-5f
#define NITER  10
#define WS_STRIDE 80   // floats per particle in ws: a[64], B at [64], pad to 80

__device__ __forceinline__ float fast_rcp(float v) {
#if __has_builtin(__builtin_amdgcn_rcpf)
    return __builtin_amdgcn_rcpf(v);
#else
    return 1.0f / v;
#endif
}

// ---------------------------------------------------------------------------
// Kernel A: solve only. 512 blocks x 256 threads, 1 particle/block.
// r20's verified fused-build + 1-barrier CG (passed: 18.2us total, absmax
// 0.0156), with ALL gamma/z/K/y streaming removed: writes a[64] + B to ws.
// No HBM traffic inside the latency-bound chain -> ~6-7us.
// ---------------------------------------------------------------------------
__global__ __launch_bounds__(256) void diag_sgp_solve(
    const float* __restrict__ x,        // (n,8)
    const float* __restrict__ inducing, // (64,8)
    const float* __restrict__ pvar,
    const float* __restrict__ pls,
    float* __restrict__ ws_a)           // (n, WS_STRIDE)
{
    const int tid = threadIdx.x;
    const int n   = blockIdx.x;

    __shared__ __align__(16) float Zl[64 * 8];
    __shared__ float xl[8];

    for (int i = tid; i < 512; i += 256) Zl[i] = inducing[i];
    if (tid < 8) xl[tid] = x[n * 8 + tid];
    const float var = pvar[0], ls = pls[0];
    const float sc = 0.5f / (ls * ls);
    __syncthreads();                               // B1

    const int row = tid >> 2;
    const int q   = tid & 3;

    float zr[8];
    {
        const float4 za = *reinterpret_cast<const float4*>(&Zl[row * 8]);
        const float4 zb = *reinterpret_cast<const float4*>(&Zl[row * 8 + 4]);
        zr[0] = za.x; zr[1] = za.y; zr[2] = za.z; zr[3] = za.w;
        zr[4] = zb.x; zr[5] = zb.y; zr[6] = zb.z; zr[7] = zb.w;
    }

    // fused build: M[i] = M[row][q*16+i], e_t[i] = e[q*16+i]
    float M_[16], e_t[16];
#pragma unroll
    for (int i = 0; i < 16; ++i) {
        const int c = q * 16 + i;
        const float4 r0 = *reinterpret_cast<const float4*>(&Zl[c * 8]);
        const float4 r1 = *reinterpret_cast<const float4*>(&Zl[c * 8 + 4]);
        float sm, se;
        {
            float d;
            d = zr[0] - r0.x; sm  = d * d;   d = xl[0] - r0.x; se  = d * d;
            d = zr[1] - r0.y; sm = fmaf(d, d, sm); d = xl[1] - r0.y; se = fmaf(d, d, se);
            d = zr[2] - r0.z; sm = fmaf(d, d, sm); d = xl[2] - r0.z; se = fmaf(d, d, se);
            d = zr[3] - r0.w; sm = fmaf(d, d, sm); d = xl[3] - r0.w; se = fmaf(d, d, se);
            d = zr[4] - r1.x; sm = fmaf(d, d, sm); d = xl[4] - r1.x; se = fmaf(d, d, se);
            d = zr[5] - r1.y; sm = fmaf(d, d, sm); d = xl[5] - r1.y; se = fmaf(d, d, se);
            d = zr[6] - r1.z; sm = fmaf(d, d, sm); d = xl[6] - r1.z; se = fmaf(d, d, se);
            d = zr[7] - r1.w; sm = fmaf(d, d, sm); d = xl[7] - r1.w; se = fmaf(d, d, se);
        }
        const float vm = __expf(-sm * sc);
        M_[i]  = (row == c) ? vm + JITTER : vm;
        e_t[i] = __expf(-se * sc);
    }

    // CG init
    __shared__ __align__(16) float Mp_lds[2][64];
    float x_t[16], r_t[16], p_t[16];
    float rz;
    {
        float s = 0.f;
#pragma unroll
        for (int i = 0; i < 16; ++i) {
            x_t[i] = 0.f;
            r_t[i] = e_t[i];
            p_t[i] = e_t[i];
            s = fmaf(e_t[i], e_t[i], s);
        }
        s += __shfl_xor(s, 1);
        s += __shfl_xor(s, 2);
        rz = s;
    }

    // 1-barrier CG loop
#pragma unroll
    for (int it = 0; it < NITER - 1; ++it) {
        const int buf = it & 1;
        {
            float mp = 0.f;
#pragma unroll
            for (int i = 0; i < 16; ++i) mp = fmaf(M_[i], p_t[i], mp);
            mp += __shfl_xor(mp, 1);
            mp += __shfl_xor(mp, 2);
            if (q == 0) Mp_lds[buf][row] = mp;
        }
        __syncthreads();

        const float4 ma = *reinterpret_cast<const float4*>(&Mp_lds[buf][q * 16 + 0]);
        const float4 mb = *reinterpret_cast<const float4*>(&Mp_lds[buf][q * 16 + 4]);
        const float4 mc = *reinterpret_cast<const float4*>(&Mp_lds[buf][q * 16 + 8]);
        const float4 md = *reinterpret_cast<const float4*>(&Mp_lds[buf][q * 16 + 12]);
        const float mpv[16] = {ma.x, ma.y, ma.z, ma.w, mb.x, mb.y, mb.z, mb.w,
                               mc.x, mc.y, mc.z, mc.w, md.x, md.y, md.z, md.w};

        float pap = 0.f;
#pragma unroll
        for (int i = 0; i < 16; ++i) pap = fmaf(p_t[i], mpv[i], pap);
        pap += __shfl_xor(pap, 1);
        pap += __shfl_xor(pap, 2);
        const float alpha = rz * fast_rcp(pap + 1e-30f);

        float rr = 0.f;
#pragma unroll
        for (int i = 0; i < 16; ++i) {
            x_t[i] = fmaf(alpha, p_t[i], x_t[i]);
            r_t[i] = fmaf(-alpha, mpv[i], r_t[i]);
            rr = fmaf(r_t[i], r_t[i], rr);
        }
        rr += __shfl_xor(rr, 1);
        rr += __shfl_xor(rr, 2);
        const float beta = rr * fast_rcp(rz + 1e-30f);
        rz = rr;
#pragma unroll
        for (int i = 0; i < 16; ++i) p_t[i] = fmaf(beta, p_t[i], r_t[i]);
    }

    // final iteration: matvec + alpha + x only
    {
        const int buf = (NITER - 1) & 1;
        float mp = 0.f;
#pragma unroll
        for (int i = 0; i < 16; ++i) mp = fmaf(M_[i], p_t[i], mp);
        mp += __shfl_xor(mp, 1);
        mp += __shfl_xor(mp, 2);
        if (q == 0) Mp_lds[buf][row] = mp;
        __syncthreads();

        const float4 ma = *reinterpret_cast<const float4*>(&Mp_lds[buf][q * 16 + 0]);
        const float4 mb = *reinterpret_cast<const float4*>(&Mp_lds[buf][q * 16 + 4]);
        const float4 mc = *reinterpret_cast<const float4*>(&Mp_lds[buf][q * 16 + 8]);
        const float4 md = *reinterpret_cast<const float4*>(&Mp_lds[buf][q * 16 + 12]);
        const float mpv[16] = {ma.x, ma.y, ma.z, ma.w, mb.x, mb.y, mb.z, mb.w,
                               mc.x, mc.y, mc.z, mc.w, md.x, md.y, md.z, md.w};
        float pap = 0.f;
#pragma unroll
        for (int i = 0; i < 16; ++i) pap = fmaf(p_t[i], mpv[i], pap);
        pap += __shfl_xor(pap, 1);
        pap += __shfl_xor(pap, 2);
        const float alpha = rz * fast_rcp(pap + 1e-30f);
#pragma unroll
        for (int i = 0; i < 16; ++i) x_t[i] = fmaf(alpha, p_t[i], x_t[i]);
    }

    // B = var*(1 - <e,a>); publish a + B to ws
    {
        float s = 0.f;
#pragma unroll
        for (int i = 0; i < 16; ++i) s = fmaf(e_t[i], x_t[i], s);
        s += __shfl_xor(s, 1);
        s += __shfl_xor(s, 2);
        float* wp = ws_a + (size_t)n * WS_STRIDE;
        if (row == 0) {                            // 4 threads write a (4xb128 each)
#pragma unroll
            for (int u = 0; u < 4; ++u)
                *reinterpret_cast<float4*>(wp + q * 16 + u * 4) =
                    make_float4(x_t[u * 4 + 0], x_t[u * 4 + 1],
                                x_t[u * 4 + 2], x_t[u * 4 + 3]);
        }
        if (tid == 0) wp[64] = var * (1.f - s);
    }
}

// ---------------------------------------------------------------------------
// Kernel B: streaming epilogue. 512 blocks x 256 threads, 1 particle/block.
// r19/r20-verified epilogue reading a,B from ws. Serial chain is 3 short
// barrier phases -> the 16.8MB gamma/z/out stream pipelines at high BW.
// ---------------------------------------------------------------------------
__global__ __launch_bounds__(256) void diag_sgp_epilogue(
    const float* __restrict__ y,        // (n,32)
    const float* __restrict__ z,        // (n,2048)
    const float* __restrict__ gamma,    // (n,2048)
    const float* __restrict__ Kmat,     // (32,32)
    const float* __restrict__ pnoise,
    const float* __restrict__ ws_a,     // (n, WS_STRIDE)
    float* __restrict__ out,            // [m_new | g]
    int n_total)
{
    const int tid = threadIdx.x;
    const int n   = blockIdx.x;

    // prefetch stream + per-particle solve results
    const size_t base = (size_t)n * 2048 + tid * 8;
    const float4 g0 = *reinterpret_cast<const float4*>(gamma + base);
    const float4 g1 = *reinterpret_cast<const float4*>(gamma + base + 4);
    const float4 zv0 = *reinterpret_cast<const float4*>(z + base);
    const float4 zv1 = *reinterpret_cast<const float4*>(z + base + 4);
    const float* wp = ws_a + (size_t)n * WS_STRIDE;
    const int ab = (tid & 7) * 8;
    const float4 a0 = *reinterpret_cast<const float4*>(wp + ab);
    const float4 a1 = *reinterpret_cast<const float4*>(wp + ab + 4);
    const float Bv  = wp[64];
    const float nv  = pnoise[0];

    __shared__ float Kl[32 * 33];
    __shared__ float yl[32];
    __shared__ float t_sh[32], rc[32], rd[32], s1s[32], s2s[32];

    for (int i = tid; i < 1024; i += 256)
        Kl[(i >> 5) * 33 + (i & 31)] = Kmat[i];
    if (tid < 32) yl[tid] = y[n * 32 + tid];

    const int jrow = tid >> 3;
    float ga[8] = {g0.x, g0.y, g0.z, g0.w, g1.x, g1.y, g1.z, g1.w};
    const float as[8] = {a0.x, a0.y, a0.z, a0.w, a1.x, a1.y, a1.z, a1.w};

    float pt = 0.f;
#pragma unroll
    for (int e = 0; e < 8; ++e) pt += as[e] * as[e] * ga[e];
    pt += __shfl_xor(pt, 1);
    pt += __shfl_xor(pt, 2);
    pt += __shfl_xor(pt, 4);
    if ((tid & 7) == 0) t_sh[jrow] = pt;
    __syncthreads();                               // B1 (t, Kl, yl ready)

    if (tid < 32) {                                // c, d per output dim
        float acc = 0.f;
        for (int jj = 0; jj < 32; ++jj) {
            const float kv = Kl[tid * 33 + jj];
            acc += kv * kv * t_sh[jj];
        }
        const float ci = Bv * Kl[tid * 34] + nv;
        const float di = acc + ci;
        rc[tid] = yl[tid] / ci;
        rd[tid] = 1.0f / di;
    }
    __syncthreads();                               // B2

    if (tid < 32) {                                // s1, s2 per j
        float sa = 0.f, sb = 0.f;
        for (int i = 0; i < 32; ++i) {
            const float kv = Kl[i * 33 + tid];
            sa += kv * rc[i];
            sb += kv * kv * rd[i];
        }
        s1s[tid] = sa;
        s2s[tid] = sb;
    }
    __syncthreads();                               // B3

    const float zv[8] = {zv0.x, zv0.y, zv0.z, zv0.w, zv1.x, zv1.y, zv1.z, zv1.w};
    const float s1j = s1s[jrow], s2j = s2s[jrow];
    float mn[8], gg[8];
#pragma unroll
    for (int e = 0; e < 8; ++e) {
        const float ge = ga[e];
        const float am = as[e];
        const float gm = ge * am;
        const float gv = ge - gm * gm * s2j;
        gg[e] = gv;
        mn[e] = gv * (zv[e] / ge + am * s1j);
    }

    float* o_m = out + base;
    float* o_g = out + (size_t)n_total * 2048 + base;
    *reinterpret_cast<float4*>(o_m)     = make_float4(mn[0], mn[1], mn[2], mn[3]);
    *reinterpret_cast<float4*>(o_m + 4) = make_float4(mn[4], mn[5], mn[6], mn[7]);
    *reinterpret_cast<float4*>(o_g)     = make_float4(gg[0], gg[1], gg[2], gg[3]);
    *reinterpret_cast<float4*>(o_g + 4) = make_float4(gg[4], gg[5], gg[6], gg[7]);
}

extern "C" void kernel_launch(void* const* d_in, const int* in_sizes, int n_in,
                              void* d_out, int out_size, void* d_ws, size_t ws_size,
                              hipStream_t stream)
{
    const float* x        = (const float*)d_in[0];
    const float* y        = (const float*)d_in[1];
    const float* z        = (const float*)d_in[2];
    const float* gamma    = (const float*)d_in[3];
    const float* inducing = (const float*)d_in[4];
    const float* Kmat     = (const float*)d_in[5];
    const float* pvar     = (const float*)d_in[6];
    const float* pls      = (const float*)d_in[7];
    const float* pnoise   = (const float*)d_in[8];
    float* out  = (float*)d_out;
    float* ws_a = (float*)d_ws;          // 512*80*4 = 160 KB (L2-resident)

    const int n = in_sizes[0] / 8;       // 512

    diag_sgp_solve<<<dim3(n), dim3(256), 0, stream>>>(x, inducing, pvar, pls, ws_a);
    diag_sgp_epilogue<<<dim3(n), dim3(256), 0, stream>>>(
        y, z, gamma, Kmat, pnoise, ws_a, out, n);
}